// Round 7
// baseline (466.265 us; speedup 1.0000x reference)
//
#include <hip/hip_runtime.h>

typedef unsigned short ushort_t;
typedef __attribute__((ext_vector_type(8))) short short8;
typedef __attribute__((ext_vector_type(4))) float float4v;

#define E_N   4096
#define H_N   512
#define NH_N  4
#define HD_N  128
#define FFN_N 1024
#define H3_N  1536

__device__ __forceinline__ float bf2f(ushort_t u) {
  union { unsigned u; float f; } v; v.u = ((unsigned)u) << 16; return v.f;
}
__device__ __forceinline__ ushort_t f2bf(float f) {
  union { float f; unsigned u; } v; v.f = f;
  unsigned r = v.u + 0x7fffu + ((v.u >> 16) & 1u);
  return (ushort_t)(r >> 16);
}
// 8 consecutive fp32 -> 8 bf16 packed into uint4
__device__ __forceinline__ uint4 cvt8(const float* p) {
  float4 a = *(const float4*)p;
  float4 b = *(const float4*)(p + 4);
  union { ushort_t u[8]; uint4 v; } pk;
  pk.u[0] = f2bf(a.x); pk.u[1] = f2bf(a.y); pk.u[2] = f2bf(a.z); pk.u[3] = f2bf(a.w);
  pk.u[4] = f2bf(b.x); pk.u[5] = f2bf(b.y); pk.u[6] = f2bf(b.z); pk.u[7] = f2bf(b.w);
  return pk.v;
}
__device__ __forceinline__ uint4 cvt8v(float4 a, float4 b) {
  union { ushort_t u[8]; uint4 v; } pk;
  pk.u[0] = f2bf(a.x); pk.u[1] = f2bf(a.y); pk.u[2] = f2bf(a.z); pk.u[3] = f2bf(a.w);
  pk.u[4] = f2bf(b.x); pk.u[5] = f2bf(b.y); pk.u[6] = f2bf(b.z); pk.u[7] = f2bf(b.w);
  return pk.v;
}

// ---------------------------------------------------------------------------
// prep: fused {zero agg (blocks 0..2047)} + {fp32->bf16 weight convert
// (blocks 2048..3839)} + {out init = b_f2 (blocks 3840..3855)}.
// ---------------------------------------------------------------------------
__global__ __launch_bounds__(256) void prep_kernel(
    const float* __restrict__ wmsg, const float* __restrict__ wih,
    const float* __restrict__ whh,  const float* __restrict__ win,
    const float* __restrict__ wout, const float* __restrict__ wlin,
    const float* __restrict__ wf1,  ushort_t* __restrict__ wdst,
    float4* __restrict__ agg, const float* __restrict__ b2,
    float* __restrict__ out)
{
  int b = blockIdx.x;
  if (b < 2048) {
    agg[(size_t)b * 256 + threadIdx.x] = make_float4(0.f, 0.f, 0.f, 0.f);
    return;
  }
  if (b < 3840) {
    size_t o = ((size_t)(b - 2048) * 256 + threadIdx.x) * 8;
    const float* s;
    if      (o <  262144) s = wmsg + o;
    else if (o < 1048576) s = wih  + (o -  262144);
    else if (o < 1835008) s = whh  + (o - 1048576);
    else if (o < 2621440) s = win  + (o - 1835008);
    else if (o < 2883584) s = wout + (o - 2621440);
    else if (o < 3145728) s = wlin + (o - 2883584);
    else                  s = wf1  + (o - 3145728);
    *(uint4*)(wdst + o) = cvt8(s);
    return;
  }
  int i = (b - 3840) * 256 + threadIdx.x;   // 0..4095
  out[i] = b2[0];
}

// ---------------------------------------------------------------------------
// bf16-MFMA GEMM: C[m][n] = epilogue( sum_k A[m][k] * W[n][k] + bias[n] )
// W pre-converted bf16 [N,K]. ASRC: 0 = bf16 A, 1 = fp32 A (cvt at ds_write).
// 128x64 tile, BK=64, 4 waves (2x2), DOUBLE-BUFFERED LDS, one barrier/iter.
// LDS rows 128B, XOR-swizzled (byte ^= (row&7)<<4).  48 KB LDS, 3 blocks/CU.
// MODE_F1 fuses the final dot with W_f2: shfl-reduce + atomicAdd to out.
// ---------------------------------------------------------------------------
enum { MODE_MSG = 0, MODE_GI = 1, MODE_GH = 2, MODE_QKV = 3, MODE_OUT = 4,
       MODE_LIN = 5, MODE_F1 = 6 };

template <int MODE, int ASRC>
__global__ __launch_bounds__(256, 3) void gemm_bt(
    const void* __restrict__ Av, const ushort_t* __restrict__ W,
    const float* __restrict__ bias, int K,
    float* __restrict__ outf, ushort_t* __restrict__ outb,
    const int* __restrict__ edge, float* __restrict__ aggf,
    const ushort_t* __restrict__ hres,
    ushort_t* __restrict__ qb, ushort_t* __restrict__ kb,
    ushort_t* __restrict__ vt, const float* __restrict__ wf2)
{
  __shared__ ushort_t As[2][128 * 64];
  __shared__ ushort_t Bs[2][64 * 64];
  char* AsB = (char*)As;
  char* BsB = (char*)Bs;

  const int tid  = threadIdx.x;
  const int lane = tid & 63;
  const int wave = tid >> 6;
  const int quad = lane >> 4;
  const int l15  = lane & 15;
  const int m0 = blockIdx.x * 128;
  const int n0 = blockIdx.y * 64;
  const int wm = (wave >> 1) * 64;
  const int wn = (wave & 1) * 32;

  float4v acc[4][2];
#pragma unroll
  for (int i = 0; i < 4; i++)
#pragma unroll
    for (int j = 0; j < 2; j++)
#pragma unroll
      for (int r = 0; r < 4; r++) acc[i][j][r] = 0.f;

  // staging coords: thread covers rows {ar+32i}, 8 cols at ac.
  const int ar = tid >> 3;
  const int ac = (tid & 7) * 8;
  const int awb = (ac * 2) ^ ((ar & 7) << 4);   // swizzled byte col (write)
  const int rmask = (l15 & 7) << 4;             // read-side swizzle mask

  uint4  pa[4], pb[2];
  float4 fa[8];

#define LOADA(KK)                                                              \
  do {                                                                         \
    if constexpr (ASRC == 0) {                                                 \
      const ushort_t* Ab = (const ushort_t*)Av;                                \
      _Pragma("unroll")                                                        \
      for (int i = 0; i < 4; i++)                                              \
        pa[i] = *(const uint4*)(Ab + (size_t)(m0 + ar + 32 * i) * K + (KK) + ac); \
    } else {                                                                   \
      const float* Af = (const float*)Av;                                      \
      _Pragma("unroll")                                                        \
      for (int i = 0; i < 4; i++) {                                            \
        const float* p = Af + (size_t)(m0 + ar + 32 * i) * K + (KK) + ac;      \
        fa[2 * i]     = *(const float4*)(p);                                   \
        fa[2 * i + 1] = *(const float4*)(p + 4);                               \
      }                                                                        \
    }                                                                          \
  } while (0)

#define LOADB(KK)                                                              \
  do {                                                                         \
    _Pragma("unroll")                                                          \
    for (int i = 0; i < 2; i++)                                                \
      pb[i] = *(const uint4*)(W + (size_t)(n0 + ar + 32 * i) * K + (KK) + ac); \
  } while (0)

#define WRITEAB(BUF)                                                           \
  do {                                                                         \
    _Pragma("unroll")                                                          \
    for (int i = 0; i < 4; i++) {                                              \
      uint4 v_;                                                                \
      if constexpr (ASRC == 0) v_ = pa[i];                                     \
      else                     v_ = cvt8v(fa[2 * i], fa[2 * i + 1]);           \
      *(uint4*)(AsB + (BUF) * 16384 + (ar + 32 * i) * 128 + awb) = v_;         \
    }                                                                          \
    _Pragma("unroll")                                                          \
    for (int i = 0; i < 2; i++)                                                \
      *(uint4*)(BsB + (BUF) * 8192 + (ar + 32 * i) * 128 + awb) = pb[i];       \
  } while (0)

  LOADA(0);
  LOADB(0);
  WRITEAB(0);
  int cur = 0;

  for (int k0 = 0; k0 < K; k0 += 64) {
    const bool more = (k0 + 64 < K);
    if (more) { LOADA(k0 + 64); LOADB(k0 + 64); }
    __syncthreads();

#pragma unroll
    for (int ks = 0; ks < 2; ks++) {
      short8 af[4], bfr[2];
#pragma unroll
      for (int i = 0; i < 4; i++)
        af[i] = *(const short8*)(AsB + cur * 16384 +
                 (wm + i * 16 + l15) * 128 + ((ks * 64 + quad * 16) ^ rmask));
#pragma unroll
      for (int j = 0; j < 2; j++)
        bfr[j] = *(const short8*)(BsB + cur * 8192 +
                 (wn + j * 16 + l15) * 128 + ((ks * 64 + quad * 16) ^ rmask));
#pragma unroll
      for (int i = 0; i < 4; i++)
#pragma unroll
        for (int j = 0; j < 2; j++)
          acc[i][j] = __builtin_amdgcn_mfma_f32_16x16x32_bf16(af[i], bfr[j],
                                                              acc[i][j], 0, 0, 0);
    }

    if (more) WRITEAB(cur ^ 1);
    cur ^= 1;
  }
#undef LOADA
#undef LOADB
#undef WRITEAB

  if constexpr (MODE == MODE_F1) {
    // fused: out[row] += sum_col relu(f1) * wf2[col]  (out pre-init'd to b_f2)
    float fsum[4][4];
#pragma unroll
    for (int i = 0; i < 4; i++)
#pragma unroll
      for (int r = 0; r < 4; r++) fsum[i][r] = 0.f;
#pragma unroll
    for (int j = 0; j < 2; j++) {
      const int col = n0 + wn + j * 16 + l15;
      const float bv = bias[col];
      const float wv = wf2[col];
#pragma unroll
      for (int i = 0; i < 4; i++)
#pragma unroll
        for (int r = 0; r < 4; r++)
          fsum[i][r] += fmaxf(acc[i][j][r] + bv, 0.f) * wv;
    }
#pragma unroll
    for (int i = 0; i < 4; i++)
#pragma unroll
      for (int r = 0; r < 4; r++) {
        float s = fsum[i][r];
        s += __shfl_xor(s, 1, 64); s += __shfl_xor(s, 2, 64);
        s += __shfl_xor(s, 4, 64); s += __shfl_xor(s, 8, 64);
        if (l15 == 0)
          atomicAdd(&outf[m0 + wm + i * 16 + quad * 4 + r], s);
      }
  } else {
#pragma unroll
    for (int j = 0; j < 2; j++) {
      const int col = n0 + wn + j * 16 + l15;
      const float bv = bias[col];
#pragma unroll
      for (int i = 0; i < 4; i++) {
#pragma unroll
        for (int r = 0; r < 4; r++) {
          const int row = m0 + wm + i * 16 + quad * 4 + r;
          float v = acc[i][j][r] + bv;
          if constexpr (MODE == MODE_MSG) {
            v = fmaxf(v, 0.f);
            const int dst = edge[E_N + row] & (E_N - 1);  // edge_index[1][row]
            atomicAdd(&aggf[(size_t)dst * H_N + col], v);
          } else if constexpr (MODE == MODE_GI || MODE == MODE_GH) {
            outb[(size_t)row * H3_N + col] = f2bf(v);
          } else if constexpr (MODE == MODE_QKV) {
            const int part = col >> 9;         // 0=q 1=k 2=v
            const int hh   = (col >> 7) & 3;
            const int d    = col & 127;
            const ushort_t bvv = f2bf(v);
            if (part == 0)      qb[((size_t)hh * E_N + row) * HD_N + d] = bvv;
            else if (part == 1) kb[((size_t)hh * E_N + row) * HD_N + d] = bvv;
            else                vt[((size_t)hh * HD_N + d) * E_N + row] = bvv;  // V^T
          } else if constexpr (MODE == MODE_OUT) {
            v += bf2f(hres[(size_t)row * H_N + col]);   // residual y = o + h
            outf[(size_t)row * H_N + col] = v;
          } else {  // MODE_LIN
            outb[(size_t)row * H_N + col] = f2bf(fmaxf(v, 0.f));
          }
        }
      }
    }
  }
}

// ---------------------------------------------------------------------------
// Flash attention v7 = r6 (swizzled LDS, no-spill) + T14 reg-prefetch +
// head-per-XCD remap.  Rationale (r6 post-mortem): in the 2-barrier staging
// structure the critical path is EXPOSED staging latency, not conflicts;
// r3 showed prefetch alone is null because it moves the critical path onto
// conflicted LDS reads.  Combo: prefetch next K/V tile into registers right
// after the tile-ready barrier (consumed by ds_write at next iter top --
// r3-proven spill-free liveness), swizzled conflict-free reads (r6-proven),
// head = bid&3 so each XCD serves one head (r2-proven: K/V L2-resident,
// FETCH 35->18 MB, staging ~200cy L2 instead of ~700cy HBM).
// NO setprio, NO LDS double-buffer (r4/r5 spill triggers).
// 512 threads = 8 waves; waves 0-3: KV [0,2048), waves 4-7: KV [2048,4096);
// in-LDS flash merge at end.  80 KB LDS.
// ---------------------------------------------------------------------------
__global__ __launch_bounds__(512, 2) void attn_kernel(
    const ushort_t* __restrict__ Qg, const ushort_t* __restrict__ Kg,
    const ushort_t* __restrict__ Vtg, ushort_t* __restrict__ Ob)
{
  const int bid  = blockIdx.x;
  const int head = bid & 3;
  const int qb0  = (bid >> 2) * 64;
  const int tid  = threadIdx.x;
  const int wave = tid >> 6;
  const int grp  = wave >> 2;     // 0/1: which KV half
  const int w4   = wave & 3;      // which 16-row Q sub-tile
  const int gtid = tid & 255;     // thread id within group (staging)
  const int lane = tid & 63;
  const int quad = lane >> 4;
  const int l15  = lane & 15;

  __shared__ ushort_t Ks[2][64][128];   // [grp], swizzled, 32768 B
  __shared__ ushort_t Vs[2][128][64];   // [grp], swizzled, 32768 B
  __shared__ ushort_t Ps[8][16][64];    // per-wave, swizzled, 16384 B
  char* KsB = (char*)Ks + grp * 16384;
  char* VsB = (char*)Vs + grp * 16384;
  char* Psc = (char*)Ps + wave * 2048;

  const ushort_t* Qhead  = Qg  + (size_t)head * E_N * HD_N;
  const ushort_t* Khead  = Kg  + (size_t)head * E_N * HD_N;
  const ushort_t* Vthead = Vtg + (size_t)head * HD_N * E_N;

  // Q A-fragments: loop-invariant, in registers.
  short8 aq[4];
#pragma unroll
  for (int ks = 0; ks < 4; ks++)
    aq[ks] = *(const short8*)(Qhead +
        (size_t)(qb0 + w4 * 16 + l15) * HD_N + ks * 32 + quad * 8);

  float4v oacc[8];
#pragma unroll
  for (int i = 0; i < 8; i++)
#pragma unroll
    for (int r = 0; r < 4; r++) oacc[i][r] = 0.f;
  float mprev[4], lsum[4];
#pragma unroll
  for (int r = 0; r < 4; r++) { mprev[r] = -1e30f; lsum[r] = 0.f; }

  const float scale = 0.088388347648318447f;  // 1/sqrt(128)
  const int q15sw = (l15 & 7) << 4;           // read-side swizzle mask

  // staging coords (fixed per-thread; row low-3-bits invariant under +16i/+32i)
  const int gr  = gtid >> 4;            // K rows gr+16i
  const int kcb = (gtid & 15) * 16;     // K col byte
  const int ksw = (gr & 7) << 4;        // K write swizzle
  const int vrr = gtid >> 3;            // V rows vrr+32i
  const int vcb = (gtid & 7) * 16;      // V col byte
  const int vsw = (vrr & 7) << 4;

  const int kt0 = grp * 2048;
  uint4 kr[4], vr[4];

#define LOADKV(KT)                                                             \
  do {                                                                         \
    _Pragma("unroll")                                                          \
    for (int i = 0; i < 4; i++) {                                              \
      kr[i] = *(const uint4*)(Khead + (size_t)((KT) + gr + 16 * i) * HD_N + (kcb >> 1)); \
      vr[i] = *(const uint4*)(Vthead + (size_t)(vrr + 32 * i) * E_N + (KT) + (vcb >> 1)); \
    }                                                                          \
  } while (0)

  LOADKV(kt0);   // prologue: tile 0 into registers

  for (int it = 0; it < 32; it++) {
    __syncthreads();   // all waves done reading previous tile
#pragma unroll
    for (int i = 0; i < 4; i++) {
      *(uint4*)(KsB + (gr + 16 * i) * 256 + (kcb ^ ksw)) = kr[i];
      *(uint4*)(VsB + (vrr + 32 * i) * 128 + (vcb ^ vsw)) = vr[i];
    }
    __syncthreads();   // tile ready

    // prefetch NEXT tile into registers: latency hides under compute below,
    // consumed by the ds_write after the next barrier (r3-proven liveness).
    if (it + 1 < 32) LOADKV(kt0 + (it + 1) * 64);

    float4v sacc[4];
#pragma unroll
    for (int j = 0; j < 4; j++)
#pragma unroll
      for (int r = 0; r < 4; r++) sacc[j][r] = 0.f;
#pragma unroll
    for (int ks = 0; ks < 4; ks++) {
#pragma unroll
      for (int j = 0; j < 4; j++) {
        short8 bk = *(const short8*)(KsB + (j * 16 + l15) * 256 +
                                     ((ks * 64 + quad * 16) ^ q15sw));
        sacc[j] = __builtin_amdgcn_mfma_f32_16x16x32_bf16(aq[ks], bk, sacc[j], 0, 0, 0);
      }
    }

    float alpha[4], pv[4][4];
#pragma unroll
    for (int r = 0; r < 4; r++) {
      float mx = -1e30f;
#pragma unroll
      for (int j = 0; j < 4; j++) { float s = sacc[j][r] * scale; pv[j][r] = s; mx = fmaxf(mx, s); }
#pragma unroll
      for (int off = 1; off < 16; off <<= 1) mx = fmaxf(mx, __shfl_xor(mx, off, 64));
      float mnew = fmaxf(mprev[r], mx);
      alpha[r] = __expf(mprev[r] - mnew);
      float ss = 0.f;
#pragma unroll
      for (int j = 0; j < 4; j++) { float p = __expf(pv[j][r] - mnew); pv[j][r] = p; ss += p; }
#pragma unroll
      for (int off = 1; off < 16; off <<= 1) ss += __shfl_xor(ss, off, 64);
      lsum[r] = lsum[r] * alpha[r] + ss;
      mprev[r] = mnew;
    }
#pragma unroll
    for (int i = 0; i < 8; i++)
#pragma unroll
      for (int r = 0; r < 4; r++) oacc[i][r] *= alpha[r];

    // Ps write (wave-private, swizzled): no barrier needed (within-wave order)
#pragma unroll
    for (int j = 0; j < 4; j++)
#pragma unroll
      for (int r = 0; r < 4; r++) {
        const int prow = quad * 4 + r;
        *(ushort_t*)(Psc + prow * 128 +
                     ((2 * (j * 16 + l15)) ^ ((prow & 7) << 4))) = f2bf(pv[j][r]);
      }

#pragma unroll
    for (int ks2 = 0; ks2 < 2; ks2++) {
      short8 ap = *(const short8*)(Psc + l15 * 128 +
                                   ((ks2 * 64 + quad * 16) ^ q15sw));
#pragma unroll
      for (int j = 0; j < 8; j++) {
        short8 bv = *(const short8*)(VsB + (j * 16 + l15) * 128 +
                                     ((ks2 * 64 + quad * 16) ^ q15sw));
        oacc[j] = __builtin_amdgcn_mfma_f32_16x16x32_bf16(ap, bv, oacc[j], 0, 0, 0);
      }
    }
  }
#undef LOADKV

  // ---- merge the two KV halves (flash combine), group1 -> LDS -> group0 ----
  __syncthreads();
  float* mO  = (float*)Ks;   // [64][128] fp32 = 32768 B (all of Ks)
  float* mML = (float*)Vs;   // [64][2]   fp32
  if (grp == 1) {
#pragma unroll
    for (int j = 0; j < 8; j++)
#pragma unroll
      for (int r = 0; r < 4; r++)
        mO[(w4 * 16 + quad * 4 + r) * 128 + j * 16 + l15] = oacc[j][r];
    if (l15 == 0) {
#pragma unroll
      for (int r = 0; r < 4; r++) {
        mML[(w4 * 16 + quad * 4 + r) * 2 + 0] = mprev[r];
        mML[(w4 * 16 + quad * 4 + r) * 2 + 1] = lsum[r];
      }
    }
  }
  __syncthreads();
  if (grp == 0) {
    float s0[4], s1[4];
#pragma unroll
    for (int r = 0; r < 4; r++) {
      int rr = w4 * 16 + quad * 4 + r;
      float m1 = mML[rr * 2 + 0], l1 = mML[rr * 2 + 1];
      float m  = fmaxf(mprev[r], m1);
      float e0 = __expf(mprev[r] - m);
      float e1 = __expf(m1 - m);
      float inv = 1.f / (lsum[r] * e0 + l1 * e1);
      s0[r] = e0 * inv;
      s1[r] = e1 * inv;
    }
#pragma unroll
    for (int j = 0; j < 8; j++)
#pragma unroll
      for (int r = 0; r < 4; r++) {
        int row = qb0 + w4 * 16 + quad * 4 + r;
        int col = head * HD_N + j * 16 + l15;
        float o1 = mO[(w4 * 16 + quad * 4 + r) * 128 + j * 16 + l15];
        Ob[(size_t)row * H_N + col] = f2bf(oacc[j][r] * s0[r] + o1 * s1[r]);
      }
  }
}

// ---------------------------------------------------------------------------
// GRU elementwise, vectorized: each thread handles 8 contiguous cols.
__global__ __launch_bounds__(256) void gru_kernel(
    const ushort_t* __restrict__ gib, const ushort_t* __restrict__ ghb,
    const float* __restrict__ x, ushort_t* __restrict__ hb) {
  int t = blockIdx.x * 256 + threadIdx.x;         // E*H/8 threads
  int e = t >> 6, j8 = (t & 63) * 8;
  size_t b = (size_t)e * H3_N + j8;
  short8 vir = *(const short8*)(gib + b);
  short8 viz = *(const short8*)(gib + b + 512);
  short8 vin = *(const short8*)(gib + b + 1024);
  short8 vhr = *(const short8*)(ghb + b);
  short8 vhz = *(const short8*)(ghb + b + 512);
  short8 vhn = *(const short8*)(ghb + b + 1024);
  size_t xo = (size_t)e * H_N + j8;
  float4 x0 = *(const float4*)(x + xo);
  float4 x1 = *(const float4*)(x + xo + 4);
  float xv[8] = {x0.x, x0.y, x0.z, x0.w, x1.x, x1.y, x1.z, x1.w};
  union { ushort_t u[8]; uint4 v; } o;
#pragma unroll
  for (int i = 0; i < 8; i++) {
    float ir = bf2f((ushort_t)vir[i]), iz = bf2f((ushort_t)viz[i]), inn = bf2f((ushort_t)vin[i]);
    float hr = bf2f((ushort_t)vhr[i]), hz = bf2f((ushort_t)vhz[i]), hn  = bf2f((ushort_t)vhn[i]);
    float r = 1.f / (1.f + __expf(-(ir + hr)));
    float z = 1.f / (1.f + __expf(-(iz + hz)));
    float n = tanhf(inn + r * hn);
    o.u[i] = f2bf((1.f - z) * n + z * xv[i]);
  }
  *(uint4*)(hb + xo) = o.v;
}

__global__ __launch_bounds__(256) void ln_kernel(
    const float* __restrict__ y, const float* __restrict__ g,
    const float* __restrict__ b, ushort_t* __restrict__ yn) {
  int wave = threadIdx.x >> 6, lane = threadIdx.x & 63;
  int row = blockIdx.x * 4 + wave;
  const float* yr = y + (size_t)row * H_N;
  float v[8], s = 0.f;
#pragma unroll
  for (int i = 0; i < 8; i++) { v[i] = yr[lane + i * 64]; s += v[i]; }
#pragma unroll
  for (int off = 1; off < 64; off <<= 1) s += __shfl_xor(s, off, 64);
  float mu = s * (1.f / 512.f);
  float q = 0.f;
#pragma unroll
  for (int i = 0; i < 8; i++) { float d = v[i] - mu; q += d * d; }
#pragma unroll
  for (int off = 1; off < 64; off <<= 1) q += __shfl_xor(q, off, 64);
  float rstd = rsqrtf(q * (1.f / 512.f) + 1e-5f);
#pragma unroll
  for (int i = 0; i < 8; i++) {
    int c = lane + i * 64;
    yn[(size_t)row * H_N + c] = f2bf((v[i] - mu) * rstd * g[c] + b[c]);
  }
}

// ---------------------------------------------------------------------------
extern "C" void kernel_launch(void* const* d_in, const int* in_sizes, int n_in,
                              void* d_out, int out_size, void* d_ws, size_t ws_size,
                              hipStream_t stream) {
  const float* x     = (const float*)d_in[0];
  const int*   edge  = (const int*)d_in[1];
  const float* W_msg = (const float*)d_in[2];
  const float* b_msg = (const float*)d_in[3];
  const float* W_ih  = (const float*)d_in[4];
  const float* b_ih  = (const float*)d_in[5];
  const float* W_hh  = (const float*)d_in[6];
  const float* b_hh  = (const float*)d_in[7];
  const float* W_in  = (const float*)d_in[8];
  const float* b_in  = (const float*)d_in[9];
  const float* W_out = (const float*)d_in[10];
  const float* b_out = (const float*)d_in[11];
  const float* ln_g  = (const float*)d_in[12];
  const float* ln_b  = (const float*)d_in[13];
  const float* W_lin = (const float*)d_in[14];
  const float* b_lin = (const float*)d_in[15];
  const float* W_f1  = (const float*)d_in[16];
  const float* b_f1  = (const float*)d_in[17];
  const float* W_f2  = (const float*)d_in[18];
  const float* b_f2  = (const float*)d_in[19];

  char* ws = (char*)d_ws;
  const size_t MB = 1024 * 1024;
  // Workspace (liveness-packed), bf16 weights at [33,40).
  float*    agg = (float*)(ws + 1 * MB);           // [1,9)   prep..GI
  ushort_t* hb  = (ushort_t*)(ws + 1 * MB);        // [1,5)   gru..OUT (agg dead)
  ushort_t* gib = (ushort_t*)(ws + 9 * MB);        // [9,21)  bf16 [E][3H], GI..gru
  ushort_t* ghb = (ushort_t*)(ws + 21 * MB);       // [21,33) bf16 [E][3H], GH..gru
  ushort_t* Qb  = (ushort_t*)(ws + 5 * MB);        // [5,9)   QKV..attn
  ushort_t* Kb  = (ushort_t*)(ws + 9 * MB);        // [9,13)  (gib dead)
  ushort_t* Vt  = (ushort_t*)(ws + 13 * MB);       // [13,17)
  ushort_t* ob  = (ushort_t*)(ws + 17 * MB);       // [17,21) attn..OUT
  float*    y   = (float*)(ws + 21 * MB);          // [21,29) fp32, OUT..ln (ghb dead)
  ushort_t* ynb = (ushort_t*)(ws + 29 * MB);       // [29,31) ln..LIN
  ushort_t* gb  = (ushort_t*)(ws + 31 * MB);       // [31,33) LIN..F1
  ushort_t* wbf = (ushort_t*)(ws + 33 * MB);       // [33,40) bf16 weights
  ushort_t* Wmsg_b = wbf;                          //  262144 elems
  ushort_t* Wih_b  = wbf + 262144;                 //  786432
  ushort_t* Whh_b  = wbf + 1048576;                //  786432
  ushort_t* Win_b  = wbf + 1835008;                //  786432
  ushort_t* Wout_b = wbf + 2621440;                //  262144
  ushort_t* Wlin_b = wbf + 2883584;                //  262144
  ushort_t* Wf1_b  = wbf + 3145728;                //  524288

  prep_kernel<<<3856, 256, 0, stream>>>(
      W_msg, W_ih, W_hh, W_in, W_out, W_lin, W_f1, wbf,
      (float4*)agg, b_f2, (float*)d_out);

  gemm_bt<MODE_MSG, 1><<<dim3(32, 8), 256, 0, stream>>>(
      x, Wmsg_b, b_msg, H_N, nullptr, nullptr, edge, agg, nullptr,
      nullptr, nullptr, nullptr, nullptr);

  gemm_bt<MODE_GI, 1><<<dim3(32, 24), 256, 0, stream>>>(
      agg, Wih_b, b_ih, H_N, nullptr, gib, nullptr, nullptr, nullptr,
      nullptr, nullptr, nullptr, nullptr);

  gemm_bt<MODE_GH, 1><<<dim3(32, 24), 256, 0, stream>>>(
      x, Whh_b, b_hh, H_N, nullptr, ghb, nullptr, nullptr, nullptr,
      nullptr, nullptr, nullptr, nullptr);

  gru_kernel<<<1024, 256, 0, stream>>>(gib, ghb, x, hb);

  gemm_bt<MODE_QKV, 0><<<dim3(32, 24), 256, 0, stream>>>(
      hb, Win_b, b_in, H_N, nullptr, nullptr, nullptr, nullptr, nullptr,
      Qb, Kb, Vt, nullptr);

  attn_kernel<<<256, 512, 0, stream>>>(Qb, Kb, Vt, ob);

  gemm_bt<MODE_OUT, 0><<<dim3(32, 8), 256, 0, stream>>>(
      ob, Wout_b, b_out, H_N, y, nullptr, nullptr, nullptr, hb,
      nullptr, nullptr, nullptr, nullptr);

  ln_kernel<<<1024, 256, 0, stream>>>(y, ln_g, ln_b, ynb);

  gemm_bt<MODE_LIN, 0><<<dim3(32, 8), 256, 0, stream>>>(
      ynb, Wlin_b, b_lin, H_N, nullptr, gb, nullptr, nullptr, nullptr,
      nullptr, nullptr, nullptr, nullptr);

  gemm_bt<MODE_F1, 0><<<dim3(32, 16), 256, 0, stream>>>(
      gb, Wf1_b, b_f1, H_N, (float*)d_out, nullptr, nullptr, nullptr, nullptr,
      nullptr, nullptr, nullptr, W_f2);
}

// Round 8
// 340.345 us; speedup vs baseline: 1.3700x; 1.3700x over previous
//
#include <hip/hip_runtime.h>

typedef unsigned short ushort_t;
typedef __attribute__((ext_vector_type(8))) short short8;
typedef __attribute__((ext_vector_type(4))) float float4v;

#define E_N   4096
#define H_N   512
#define NH_N  4
#define HD_N  128
#define FFN_N 1024
#define H3_N  1536

__device__ __forceinline__ float bf2f(ushort_t u) {
  union { unsigned u; float f; } v; v.u = ((unsigned)u) << 16; return v.f;
}
__device__ __forceinline__ ushort_t f2bf(float f) {
  union { float f; unsigned u; } v; v.f = f;
  unsigned r = v.u + 0x7fffu + ((v.u >> 16) & 1u);
  return (ushort_t)(r >> 16);
}
// 8 consecutive fp32 -> 8 bf16 packed into uint4
__device__ __forceinline__ uint4 cvt8(const float* p) {
  float4 a = *(const float4*)p;
  float4 b = *(const float4*)(p + 4);
  union { ushort_t u[8]; uint4 v; } pk;
  pk.u[0] = f2bf(a.x); pk.u[1] = f2bf(a.y); pk.u[2] = f2bf(a.z); pk.u[3] = f2bf(a.w);
  pk.u[4] = f2bf(b.x); pk.u[5] = f2bf(b.y); pk.u[6] = f2bf(b.z); pk.u[7] = f2bf(b.w);
  return pk.v;
}
__device__ __forceinline__ uint4 cvt8v(float4 a, float4 b) {
  union { ushort_t u[8]; uint4 v; } pk;
  pk.u[0] = f2bf(a.x); pk.u[1] = f2bf(a.y); pk.u[2] = f2bf(a.z); pk.u[3] = f2bf(a.w);
  pk.u[4] = f2bf(b.x); pk.u[5] = f2bf(b.y); pk.u[6] = f2bf(b.z); pk.u[7] = f2bf(b.w);
  return pk.v;
}

// global(16B/lane) -> LDS DMA: no VGPR payload (the r4/r5/r7 spill cannot occur)
__device__ __forceinline__ void gload16(const void* g, void* l) {
  __builtin_amdgcn_global_load_lds(
      (const __attribute__((address_space(1))) unsigned*)g,
      (__attribute__((address_space(3))) unsigned*)l, 16, 0, 0);
}

// ---------------------------------------------------------------------------
// prep: fused {zero agg} + {fp32->bf16 weight convert} + {out init = b_f2}.
// ---------------------------------------------------------------------------
__global__ __launch_bounds__(256) void prep_kernel(
    const float* __restrict__ wmsg, const float* __restrict__ wih,
    const float* __restrict__ whh,  const float* __restrict__ win,
    const float* __restrict__ wout, const float* __restrict__ wlin,
    const float* __restrict__ wf1,  ushort_t* __restrict__ wdst,
    float4* __restrict__ agg, const float* __restrict__ b2,
    float* __restrict__ out)
{
  int b = blockIdx.x;
  if (b < 2048) {
    agg[(size_t)b * 256 + threadIdx.x] = make_float4(0.f, 0.f, 0.f, 0.f);
    return;
  }
  if (b < 3840) {
    size_t o = ((size_t)(b - 2048) * 256 + threadIdx.x) * 8;
    const float* s;
    if      (o <  262144) s = wmsg + o;
    else if (o < 1048576) s = wih  + (o -  262144);
    else if (o < 1835008) s = whh  + (o - 1048576);
    else if (o < 2621440) s = win  + (o - 1835008);
    else if (o < 2883584) s = wout + (o - 2621440);
    else if (o < 3145728) s = wlin + (o - 2883584);
    else                  s = wf1  + (o - 3145728);
    *(uint4*)(wdst + o) = cvt8(s);
    return;
  }
  int i = (b - 3840) * 256 + threadIdx.x;   // 0..4095
  out[i] = b2[0];
}

// ---------------------------------------------------------------------------
// bf16-MFMA GEMM: unchanged from r7 (proven good: ~232us for the whole
// non-attn pipeline).  128x64 tile, BK=64, dbuf LDS, swizzled, 3 blocks/CU.
// MODE_F1 fuses the final dot with W_f2.
// ---------------------------------------------------------------------------
enum { MODE_MSG = 0, MODE_GI = 1, MODE_GH = 2, MODE_QKV = 3, MODE_OUT = 4,
       MODE_LIN = 5, MODE_F1 = 6 };

template <int MODE, int ASRC>
__global__ __launch_bounds__(256, 3) void gemm_bt(
    const void* __restrict__ Av, const ushort_t* __restrict__ W,
    const float* __restrict__ bias, int K,
    float* __restrict__ outf, ushort_t* __restrict__ outb,
    const int* __restrict__ edge, float* __restrict__ aggf,
    const ushort_t* __restrict__ hres,
    ushort_t* __restrict__ qb, ushort_t* __restrict__ kb,
    ushort_t* __restrict__ vt, const float* __restrict__ wf2)
{
  __shared__ ushort_t As[2][128 * 64];
  __shared__ ushort_t Bs[2][64 * 64];
  char* AsB = (char*)As;
  char* BsB = (char*)Bs;

  const int tid  = threadIdx.x;
  const int lane = tid & 63;
  const int wave = tid >> 6;
  const int quad = lane >> 4;
  const int l15  = lane & 15;
  const int m0 = blockIdx.x * 128;
  const int n0 = blockIdx.y * 64;
  const int wm = (wave >> 1) * 64;
  const int wn = (wave & 1) * 32;

  float4v acc[4][2];
#pragma unroll
  for (int i = 0; i < 4; i++)
#pragma unroll
    for (int j = 0; j < 2; j++)
#pragma unroll
      for (int r = 0; r < 4; r++) acc[i][j][r] = 0.f;

  const int ar = tid >> 3;
  const int ac = (tid & 7) * 8;
  const int awb = (ac * 2) ^ ((ar & 7) << 4);   // swizzled byte col (write)
  const int rmask = (l15 & 7) << 4;             // read-side swizzle mask

  uint4  pa[4], pb[2];
  float4 fa[8];

#define LOADA(KK)                                                              \
  do {                                                                         \
    if constexpr (ASRC == 0) {                                                 \
      const ushort_t* Ab = (const ushort_t*)Av;                                \
      _Pragma("unroll")                                                        \
      for (int i = 0; i < 4; i++)                                              \
        pa[i] = *(const uint4*)(Ab + (size_t)(m0 + ar + 32 * i) * K + (KK) + ac); \
    } else {                                                                   \
      const float* Af = (const float*)Av;                                      \
      _Pragma("unroll")                                                        \
      for (int i = 0; i < 4; i++) {                                            \
        const float* p = Af + (size_t)(m0 + ar + 32 * i) * K + (KK) + ac;      \
        fa[2 * i]     = *(const float4*)(p);                                   \
        fa[2 * i + 1] = *(const float4*)(p + 4);                               \
      }                                                                        \
    }                                                                          \
  } while (0)

#define LOADB(KK)                                                              \
  do {                                                                         \
    _Pragma("unroll")                                                          \
    for (int i = 0; i < 2; i++)                                                \
      pb[i] = *(const uint4*)(W + (size_t)(n0 + ar + 32 * i) * K + (KK) + ac); \
  } while (0)

#define WRITEAB(BUF)                                                           \
  do {                                                                         \
    _Pragma("unroll")                                                          \
    for (int i = 0; i < 4; i++) {                                              \
      uint4 v_;                                                                \
      if constexpr (ASRC == 0) v_ = pa[i];                                     \
      else                     v_ = cvt8v(fa[2 * i], fa[2 * i + 1]);           \
      *(uint4*)(AsB + (BUF) * 16384 + (ar + 32 * i) * 128 + awb) = v_;         \
    }                                                                          \
    _Pragma("unroll")                                                          \
    for (int i = 0; i < 2; i++)                                                \
      *(uint4*)(BsB + (BUF) * 8192 + (ar + 32 * i) * 128 + awb) = pb[i];       \
  } while (0)

  LOADA(0);
  LOADB(0);
  WRITEAB(0);
  int cur = 0;

  for (int k0 = 0; k0 < K; k0 += 64) {
    const bool more = (k0 + 64 < K);
    if (more) { LOADA(k0 + 64); LOADB(k0 + 64); }
    __syncthreads();

#pragma unroll
    for (int ks = 0; ks < 2; ks++) {
      short8 af[4], bfr[2];
#pragma unroll
      for (int i = 0; i < 4; i++)
        af[i] = *(const short8*)(AsB + cur * 16384 +
                 (wm + i * 16 + l15) * 128 + ((ks * 64 + quad * 16) ^ rmask));
#pragma unroll
      for (int j = 0; j < 2; j++)
        bfr[j] = *(const short8*)(BsB + cur * 8192 +
                 (wn + j * 16 + l15) * 128 + ((ks * 64 + quad * 16) ^ rmask));
#pragma unroll
      for (int i = 0; i < 4; i++)
#pragma unroll
        for (int j = 0; j < 2; j++)
          acc[i][j] = __builtin_amdgcn_mfma_f32_16x16x32_bf16(af[i], bfr[j],
                                                              acc[i][j], 0, 0, 0);
    }

    if (more) WRITEAB(cur ^ 1);
    cur ^= 1;
  }
#undef LOADA
#undef LOADB
#undef WRITEAB

  if constexpr (MODE == MODE_F1) {
    float fsum[4][4];
#pragma unroll
    for (int i = 0; i < 4; i++)
#pragma unroll
      for (int r = 0; r < 4; r++) fsum[i][r] = 0.f;
#pragma unroll
    for (int j = 0; j < 2; j++) {
      const int col = n0 + wn + j * 16 + l15;
      const float bv = bias[col];
      const float wv = wf2[col];
#pragma unroll
      for (int i = 0; i < 4; i++)
#pragma unroll
        for (int r = 0; r < 4; r++)
          fsum[i][r] += fmaxf(acc[i][j][r] + bv, 0.f) * wv;
    }
#pragma unroll
    for (int i = 0; i < 4; i++)
#pragma unroll
      for (int r = 0; r < 4; r++) {
        float s = fsum[i][r];
        s += __shfl_xor(s, 1, 64); s += __shfl_xor(s, 2, 64);
        s += __shfl_xor(s, 4, 64); s += __shfl_xor(s, 8, 64);
        if (l15 == 0)
          atomicAdd(&outf[m0 + wm + i * 16 + quad * 4 + r], s);
      }
  } else {
#pragma unroll
    for (int j = 0; j < 2; j++) {
      const int col = n0 + wn + j * 16 + l15;
      const float bv = bias[col];
#pragma unroll
      for (int i = 0; i < 4; i++) {
#pragma unroll
        for (int r = 0; r < 4; r++) {
          const int row = m0 + wm + i * 16 + quad * 4 + r;
          float v = acc[i][j][r] + bv;
          if constexpr (MODE == MODE_MSG) {
            v = fmaxf(v, 0.f);
            const int dst = edge[E_N + row] & (E_N - 1);  // edge_index[1][row]
            atomicAdd(&aggf[(size_t)dst * H_N + col], v);
          } else if constexpr (MODE == MODE_GI || MODE == MODE_GH) {
            outb[(size_t)row * H3_N + col] = f2bf(v);
          } else if constexpr (MODE == MODE_QKV) {
            const int part = col >> 9;         // 0=q 1=k 2=v
            const int hh   = (col >> 7) & 3;
            const int d    = col & 127;
            const ushort_t bvv = f2bf(v);
            if (part == 0)      qb[((size_t)hh * E_N + row) * HD_N + d] = bvv;
            else if (part == 1) kb[((size_t)hh * E_N + row) * HD_N + d] = bvv;
            else                vt[((size_t)hh * HD_N + d) * E_N + row] = bvv;  // V^T
          } else if constexpr (MODE == MODE_OUT) {
            v += bf2f(hres[(size_t)row * H_N + col]);   // residual y = o + h
            outf[(size_t)row * H_N + col] = v;
          } else {  // MODE_LIN
            outb[(size_t)row * H_N + col] = f2bf(fmaxf(v, 0.f));
          }
        }
      }
    }
  }
}

// ---------------------------------------------------------------------------
// Flash attention v8: K/V staged via global_load_lds DMA (NO staging VGPRs:
// the r4/r5/r7 spill mechanism cannot occur), double-buffered LDS tiles,
// ONE barrier per KV iteration.  Per iter: { barrier (drains DMA -> tile t
// ready + tile t-1 reads done); issue 8 DMA for tile t+1 into buf^1;
// compute QK/softmax/PV on buf }.  Load latency hides under the full
// compute phase (vmcnt drained only at the next barrier).
// Swizzle per rule #21: LDS dest LINEAR (base+lane*16), per-lane global
// SOURCE pre-swizzled with the same XOR involution used on the read side
// (byte ^= (row&7)<<4; swizzle is a function of (row,col) only).
// grid 256 1-D: head = bid&3 -> one head per XCD, K/V L2-resident (r2).
// 8 waves; waves 0-3: KV [0,2048), waves 4-7: KV [2048,4096); LDS merge.
// LDS: K 2x2x16KB + V 2x2x16KB + Ps 16KB = 144 KB.
// ---------------------------------------------------------------------------
__global__ __launch_bounds__(512, 2) void attn_kernel(
    const ushort_t* __restrict__ Qg, const ushort_t* __restrict__ Kg,
    const ushort_t* __restrict__ Vtg, ushort_t* __restrict__ Ob)
{
  const int bid  = blockIdx.x;
  const int head = bid & 3;
  const int qb0  = (bid >> 2) * 64;
  const int tid  = threadIdx.x;
  const int wave = tid >> 6;
  const int grp  = wave >> 2;     // 0/1: which KV half
  const int w4   = wave & 3;      // which 16-row Q sub-tile / staging chunk set
  const int lane = tid & 63;
  const int quad = lane >> 4;
  const int l15  = lane & 15;

  __shared__ ushort_t Ks[2][2][64][128];   // [grp][buf], swizzled, 65536 B
  __shared__ ushort_t Vs[2][2][128][64];   // [grp][buf], swizzled, 65536 B
  __shared__ ushort_t Ps[8][16][64];       // per-wave, swizzled, 16384 B
  char* Psc = (char*)Ps + wave * 2048;

  const ushort_t* Qhead  = Qg  + (size_t)head * E_N * HD_N;
  const ushort_t* Khead  = Kg  + (size_t)head * E_N * HD_N;
  const ushort_t* Vthead = Vtg + (size_t)head * HD_N * E_N;

  // Q A-fragments: loop-invariant, in registers.
  short8 aq[4];
#pragma unroll
  for (int ks = 0; ks < 4; ks++)
    aq[ks] = *(const short8*)(Qhead +
        (size_t)(qb0 + w4 * 16 + l15) * HD_N + ks * 32 + quad * 8);

  float4v oacc[8];
#pragma unroll
  for (int i = 0; i < 8; i++)
#pragma unroll
    for (int r = 0; r < 4; r++) oacc[i][r] = 0.f;
  float mprev[4], lsum[4];
#pragma unroll
  for (int r = 0; r < 4; r++) { mprev[r] = -1e30f; lsum[r] = 0.f; }

  const float scale = 0.088388347648318447f;  // 1/sqrt(128)
  const int q15sw = (l15 & 7) << 4;           // read-side swizzle mask

  const int kt0 = grp * 2048;

  // DMA one 64-row K/V tile into [grp][BUF].  Each wave issues 4 K-chunks +
  // 4 V-chunks of 1024 B (64 lanes x 16 B, linear LDS).  Source column is
  // pre-swizzled so that LDS slot (row, cb) holds global (row, cb^((row&7)<<4)).
#define ISSUE(KT, BUF)                                                         \
  do {                                                                         \
    char* kb_ = (char*)Ks + ((grp * 2 + (BUF)) << 14);                         \
    char* vb_ = (char*)Vs + ((grp * 2 + (BUF)) << 14);                         \
    _Pragma("unroll")                                                          \
    for (int i_ = 0; i_ < 4; i_++) {                                           \
      const int c_ = w4 * 4 + i_;                                              \
      const int krow_ = 4 * c_ + (lane >> 4);      /* tile row 0..63 */        \
      gload16(Khead + (size_t)((KT) + krow_) * HD_N +                          \
                  (((((lane & 15) * 16)) ^ ((krow_ & 7) << 4)) >> 1),          \
              kb_ + c_ * 1024);                                                \
      const int vrow_ = 8 * c_ + (lane >> 3);      /* tile row 0..127 */       \
      gload16(Vthead + (size_t)vrow_ * E_N + (KT) +                            \
                  (((((lane & 7) * 16)) ^ ((lane >> 3) << 4)) >> 1),           \
              vb_ + c_ * 1024);                                                \
    }                                                                          \
  } while (0)

  ISSUE(kt0, 0);   // prologue: tile 0
  int cur = 0;

  for (int it = 0; it < 32; it++) {
    __syncthreads();   // drains DMA (tile it ready) + tile it-1 reads done
    if (it + 1 < 32) ISSUE(kt0 + (it + 1) * 64, cur ^ 1);

    const char* kt_ = (char*)Ks + ((grp * 2 + cur) << 14);
    const char* vt_ = (char*)Vs + ((grp * 2 + cur) << 14);

    float4v sacc[4];
#pragma unroll
    for (int j = 0; j < 4; j++)
#pragma unroll
      for (int r = 0; r < 4; r++) sacc[j][r] = 0.f;
#pragma unroll
    for (int ks = 0; ks < 4; ks++) {
#pragma unroll
      for (int j = 0; j < 4; j++) {
        short8 bk = *(const short8*)(kt_ + (j * 16 + l15) * 256 +
                                     ((ks * 64 + quad * 16) ^ q15sw));
        sacc[j] = __builtin_amdgcn_mfma_f32_16x16x32_bf16(aq[ks], bk, sacc[j], 0, 0, 0);
      }
    }

    float alpha[4], pv[4][4];
#pragma unroll
    for (int r = 0; r < 4; r++) {
      float mx = -1e30f;
#pragma unroll
      for (int j = 0; j < 4; j++) { float s = sacc[j][r] * scale; pv[j][r] = s; mx = fmaxf(mx, s); }
#pragma unroll
      for (int off = 1; off < 16; off <<= 1) mx = fmaxf(mx, __shfl_xor(mx, off, 64));
      float mnew = fmaxf(mprev[r], mx);
      alpha[r] = __expf(mprev[r] - mnew);
      float ss = 0.f;
#pragma unroll
      for (int j = 0; j < 4; j++) { float p = __expf(pv[j][r] - mnew); pv[j][r] = p; ss += p; }
#pragma unroll
      for (int off = 1; off < 16; off <<= 1) ss += __shfl_xor(ss, off, 64);
      lsum[r] = lsum[r] * alpha[r] + ss;
      mprev[r] = mnew;
    }
#pragma unroll
    for (int i = 0; i < 8; i++)
#pragma unroll
      for (int r = 0; r < 4; r++) oacc[i][r] *= alpha[r];

    // Ps write (wave-private, swizzled): within-wave lgkmcnt order, no barrier
#pragma unroll
    for (int j = 0; j < 4; j++)
#pragma unroll
      for (int r = 0; r < 4; r++) {
        const int prow = quad * 4 + r;
        *(ushort_t*)(Psc + prow * 128 +
                     ((2 * (j * 16 + l15)) ^ ((prow & 7) << 4))) = f2bf(pv[j][r]);
      }

#pragma unroll
    for (int ks2 = 0; ks2 < 2; ks2++) {
      short8 ap = *(const short8*)(Psc + l15 * 128 +
                                   ((ks2 * 64 + quad * 16) ^ q15sw));
#pragma unroll
      for (int j = 0; j < 8; j++) {
        short8 bv = *(const short8*)(vt_ + (j * 16 + l15) * 128 +
                                     ((ks2 * 64 + quad * 16) ^ q15sw));
        oacc[j] = __builtin_amdgcn_mfma_f32_16x16x32_bf16(ap, bv, oacc[j], 0, 0, 0);
      }
    }
    cur ^= 1;
  }
#undef ISSUE

  // ---- merge the two KV halves (flash combine), group1 -> LDS -> group0 ----
  __syncthreads();
  float* mO  = (float*)Ks;   // [64][128] fp32 = 32768 B (Ks region is 64 KB)
  float* mML = (float*)Vs;   // [64][2]   fp32
  if (grp == 1) {
#pragma unroll
    for (int j = 0; j < 8; j++)
#pragma unroll
      for (int r = 0; r < 4; r++)
        mO[(w4 * 16 + quad * 4 + r) * 128 + j * 16 + l15] = oacc[j][r];
    if (l15 == 0) {
#pragma unroll
      for (int r = 0; r < 4; r++) {
        mML[(w4 * 16 + quad * 4 + r) * 2 + 0] = mprev[r];
        mML[(w4 * 16 + quad * 4 + r) * 2 + 1] = lsum[r];
      }
    }
  }
  __syncthreads();
  if (grp == 0) {
    float s0[4], s1[4];
#pragma unroll
    for (int r = 0; r < 4; r++) {
      int rr = w4 * 16 + quad * 4 + r;
      float m1 = mML[rr * 2 + 0], l1 = mML[rr * 2 + 1];
      float m  = fmaxf(mprev[r], m1);
      float e0 = __expf(mprev[r] - m);
      float e1 = __expf(m1 - m);
      float inv = 1.f / (lsum[r] * e0 + l1 * e1);
      s0[r] = e0 * inv;
      s1[r] = e1 * inv;
    }
#pragma unroll
    for (int j = 0; j < 8; j++)
#pragma unroll
      for (int r = 0; r < 4; r++) {
        int row = qb0 + w4 * 16 + quad * 4 + r;
        int col = head * HD_N + j * 16 + l15;
        float o1 = mO[(w4 * 16 + quad * 4 + r) * 128 + j * 16 + l15];
        Ob[(size_t)row * H_N + col] = f2bf(oacc[j][r] * s0[r] + o1 * s1[r]);
      }
  }
}

// ---------------------------------------------------------------------------
// GRU elementwise, vectorized: each thread handles 8 contiguous cols.
__global__ __launch_bounds__(256) void gru_kernel(
    const ushort_t* __restrict__ gib, const ushort_t* __restrict__ ghb,
    const float* __restrict__ x, ushort_t* __restrict__ hb) {
  int t = blockIdx.x * 256 + threadIdx.x;         // E*H/8 threads
  int e = t >> 6, j8 = (t & 63) * 8;
  size_t b = (size_t)e * H3_N + j8;
  short8 vir = *(const short8*)(gib + b);
  short8 viz = *(const short8*)(gib + b + 512);
  short8 vin = *(const short8*)(gib + b + 1024);
  short8 vhr = *(const short8*)(ghb + b);
  short8 vhz = *(const short8*)(ghb + b + 512);
  short8 vhn = *(const short8*)(ghb + b + 1024);
  size_t xo = (size_t)e * H_N + j8;
  float4 x0 = *(const float4*)(x + xo);
  float4 x1 = *(const float4*)(x + xo + 4);
  float xv[8] = {x0.x, x0.y, x0.z, x0.w, x1.x, x1.y, x1.z, x1.w};
  union { ushort_t u[8]; uint4 v; } o;
#pragma unroll
  for (int i = 0; i < 8; i++) {
    float ir = bf2f((ushort_t)vir[i]), iz = bf2f((ushort_t)viz[i]), inn = bf2f((ushort_t)vin[i]);
    float hr = bf2f((ushort_t)vhr[i]), hz = bf2f((ushort_t)vhz[i]), hn  = bf2f((ushort_t)vhn[i]);
    float r = 1.f / (1.f + __expf(-(ir + hr)));
    float z = 1.f / (1.f + __expf(-(iz + hz)));
    float n = tanhf(inn + r * hn);
    o.u[i] = f2bf((1.f - z) * n + z * xv[i]);
  }
  *(uint4*)(hb + xo) = o.v;
}

__global__ __launch_bounds__(256) void ln_kernel(
    const float* __restrict__ y, const float* __restrict__ g,
    const float* __restrict__ b, ushort_t* __restrict__ yn) {
  int wave = threadIdx.x >> 6, lane = threadIdx.x & 63;
  int row = blockIdx.x * 4 + wave;
  const float* yr = y + (size_t)row * H_N;
  float v[8], s = 0.f;
#pragma unroll
  for (int i = 0; i < 8; i++) { v[i] = yr[lane + i * 64]; s += v[i]; }
#pragma unroll
  for (int off = 1; off < 64; off <<= 1) s += __shfl_xor(s, off, 64);
  float mu = s * (1.f / 512.f);
  float q = 0.f;
#pragma unroll
  for (int i = 0; i < 8; i++) { float d = v[i] - mu; q += d * d; }
#pragma unroll
  for (int off = 1; off < 64; off <<= 1) q += __shfl_xor(q, off, 64);
  float rstd = rsqrtf(q * (1.f / 512.f) + 1e-5f);
#pragma unroll
  for (int i = 0; i < 8; i++) {
    int c = lane + i * 64;
    yn[(size_t)row * H_N + c] = f2bf((v[i] - mu) * rstd * g[c] + b[c]);
  }
}

// ---------------------------------------------------------------------------
extern "C" void kernel_launch(void* const* d_in, const int* in_sizes, int n_in,
                              void* d_out, int out_size, void* d_ws, size_t ws_size,
                              hipStream_t stream) {
  const float* x     = (const float*)d_in[0];
  const int*   edge  = (const int*)d_in[1];
  const float* W_msg = (const float*)d_in[2];
  const float* b_msg = (const float*)d_in[3];
  const float* W_ih  = (const float*)d_in[4];
  const float* b_ih  = (const float*)d_in[5];
  const float* W_hh  = (const float*)d_in[6];
  const float* b_hh  = (const float*)d_in[7];
  const float* W_in  = (const float*)d_in[8];
  const float* b_in  = (const float*)d_in[9];
  const float* W_out = (const float*)d_in[10];
  const float* b_out = (const float*)d_in[11];
  const float* ln_g  = (const float*)d_in[12];
  const float* ln_b  = (const float*)d_in[13];
  const float* W_lin = (const float*)d_in[14];
  const float* b_lin = (const float*)d_in[15];
  const float* W_f1  = (const float*)d_in[16];
  const float* b_f1  = (const float*)d_in[17];
  const float* W_f2  = (const float*)d_in[18];
  const float* b_f2  = (const float*)d_in[19];

  char* ws = (char*)d_ws;
  const size_t MB = 1024 * 1024;
  // Workspace (liveness-packed), bf16 weights at [33,40).
  float*    agg = (float*)(ws + 1 * MB);           // [1,9)   prep..GI
  ushort_t* hb  = (ushort_t*)(ws + 1 * MB);        // [1,5)   gru..OUT (agg dead)
  ushort_t* gib = (ushort_t*)(ws + 9 * MB);        // [9,21)  bf16 [E][3H], GI..gru
  ushort_t* ghb = (ushort_t*)(ws + 21 * MB);       // [21,33) bf16 [E][3H], GH..gru
  ushort_t* Qb  = (ushort_t*)(ws + 5 * MB);        // [5,9)   QKV..attn
  ushort_t* Kb  = (ushort_t*)(ws + 9 * MB);        // [9,13)  (gib dead)
  ushort_t* Vt  = (ushort_t*)(ws + 13 * MB);       // [13,17)
  ushort_t* ob  = (ushort_t*)(ws + 17 * MB);       // [17,21) attn..OUT
  float*    y   = (float*)(ws + 21 * MB);          // [21,29) fp32, OUT..ln (ghb dead)
  ushort_t* ynb = (ushort_t*)(ws + 29 * MB);       // [29,31) ln..LIN
  ushort_t* gb  = (ushort_t*)(ws + 31 * MB);       // [31,33) LIN..F1
  ushort_t* wbf = (ushort_t*)(ws + 33 * MB);       // [33,40) bf16 weights
  ushort_t* Wmsg_b = wbf;                          //  262144 elems
  ushort_t* Wih_b  = wbf + 262144;                 //  786432
  ushort_t* Whh_b  = wbf + 1048576;                //  786432
  ushort_t* Win_b  = wbf + 1835008;                //  786432
  ushort_t* Wout_b = wbf + 2621440;                //  262144
  ushort_t* Wlin_b = wbf + 2883584;                //  262144
  ushort_t* Wf1_b  = wbf + 3145728;                //  524288

  prep_kernel<<<3856, 256, 0, stream>>>(
      W_msg, W_ih, W_hh, W_in, W_out, W_lin, W_f1, wbf,
      (float4*)agg, b_f2, (float*)d_out);

  gemm_bt<MODE_MSG, 1><<<dim3(32, 8), 256, 0, stream>>>(
      x, Wmsg_b, b_msg, H_N, nullptr, nullptr, edge, agg, nullptr,
      nullptr, nullptr, nullptr, nullptr);

  gemm_bt<MODE_GI, 1><<<dim3(32, 24), 256, 0, stream>>>(
      agg, Wih_b, b_ih, H_N, nullptr, gib, nullptr, nullptr, nullptr,
      nullptr, nullptr, nullptr, nullptr);

  gemm_bt<MODE_GH, 1><<<dim3(32, 24), 256, 0, stream>>>(
      x, Whh_b, b_hh, H_N, nullptr, ghb, nullptr, nullptr, nullptr,
      nullptr, nullptr, nullptr, nullptr);

  gru_kernel<<<1024, 256, 0, stream>>>(gib, ghb, x, hb);

  gemm_bt<MODE_QKV, 0><<<dim3(32, 24), 256, 0, stream>>>(
      hb, Win_b, b_in, H_N, nullptr, nullptr, nullptr, nullptr, nullptr,
      Qb, Kb, Vt, nullptr);

  attn_kernel<<<256, 512, 0, stream>>>(Qb, Kb, Vt, ob);

  gemm_bt<MODE_OUT, 0><<<dim3(32, 8), 256, 0, stream>>>(
      ob, Wout_b, b_out, H_N, y, nullptr, nullptr, nullptr, hb,
      nullptr, nullptr, nullptr, nullptr);

  ln_kernel<<<1024, 256, 0, stream>>>(y, ln_g, ln_b, ynb);

  gemm_bt<MODE_LIN, 0><<<dim3(32, 8), 256, 0, stream>>>(
      ynb, Wlin_b, b_lin, H_N, nullptr, gb, nullptr, nullptr, nullptr,
      nullptr, nullptr, nullptr, nullptr);

  gemm_bt<MODE_F1, 0><<<dim3(32, 16), 256, 0, stream>>>(
      gb, Wf1_b, b_f1, H_N, (float*)d_out, nullptr, nullptr, nullptr, nullptr,
      nullptr, nullptr, nullptr, W_f2);
}

// Round 9
// 288.293 us; speedup vs baseline: 1.6173x; 1.1806x over previous
//
#include <hip/hip_runtime.h>

typedef unsigned short ushort_t;
typedef __attribute__((ext_vector_type(8))) short short8;
typedef __attribute__((ext_vector_type(4))) float float4v;

#define E_N   4096
#define H_N   512
#define NH_N  4
#define HD_N  128
#define FFN_N 1024
#define H3_N  1536

__device__ __forceinline__ float bf2f(ushort_t u) {
  union { unsigned u; float f; } v; v.u = ((unsigned)u) << 16; return v.f;
}
__device__ __forceinline__ ushort_t f2bf(float f) {
  union { float f; unsigned u; } v; v.f = f;
  unsigned r = v.u + 0x7fffu + ((v.u >> 16) & 1u);
  return (ushort_t)(r >> 16);
}
// 8 consecutive fp32 -> 8 bf16 packed into uint4
__device__ __forceinline__ uint4 cvt8(const float* p) {
  float4 a = *(const float4*)p;
  float4 b = *(const float4*)(p + 4);
  union { ushort_t u[8]; uint4 v; } pk;
  pk.u[0] = f2bf(a.x); pk.u[1] = f2bf(a.y); pk.u[2] = f2bf(a.z); pk.u[3] = f2bf(a.w);
  pk.u[4] = f2bf(b.x); pk.u[5] = f2bf(b.y); pk.u[6] = f2bf(b.z); pk.u[7] = f2bf(b.w);
  return pk.v;
}

// global(16B/lane) -> LDS DMA: no VGPR payload (spill mechanism cannot occur)
__device__ __forceinline__ void gload16(const void* g, void* l) {
  __builtin_amdgcn_global_load_lds(
      (const __attribute__((address_space(1))) unsigned*)g,
      (__attribute__((address_space(3))) unsigned*)l, 16, 0, 0);
}

// ---------------------------------------------------------------------------
// prep: fused {zero agg (blocks 0..2047)} + {fp32->bf16 convert of x + all
// weights into contiguous bf16 region (blocks 2048..4863)} + {out init =
// b_f2 (blocks 4864..4879)}.  Elem boundaries: x:[0,2097152)
// Wmsg:..2359296 Wih:..3145728 Whh:..3932160 Win:..4718592 Wout:..4980736
// Wlin:..5242880 Wf1:..5767168.
// ---------------------------------------------------------------------------
__global__ __launch_bounds__(256) void prep_kernel(
    const float* __restrict__ x,
    const float* __restrict__ wmsg, const float* __restrict__ wih,
    const float* __restrict__ whh,  const float* __restrict__ win,
    const float* __restrict__ wout, const float* __restrict__ wlin,
    const float* __restrict__ wf1,  ushort_t* __restrict__ dst,
    float4* __restrict__ agg, const float* __restrict__ b2,
    float* __restrict__ out)
{
  int b = blockIdx.x;
  if (b < 2048) {
    agg[(size_t)b * 256 + threadIdx.x] = make_float4(0.f, 0.f, 0.f, 0.f);
    return;
  }
  if (b < 4864) {
    size_t o = ((size_t)(b - 2048) * 256 + threadIdx.x) * 8;
    const float* s;
    if      (o < 2097152) s = x    + o;
    else if (o < 2359296) s = wmsg + (o - 2097152);
    else if (o < 3145728) s = wih  + (o - 2359296);
    else if (o < 3932160) s = whh  + (o - 3145728);
    else if (o < 4718592) s = win  + (o - 3932160);
    else if (o < 4980736) s = wout + (o - 4718592);
    else if (o < 5242880) s = wlin + (o - 4980736);
    else                  s = wf1  + (o - 5242880);
    *(uint4*)(dst + o) = cvt8(s);
    return;
  }
  int i = (b - 4864) * 256 + threadIdx.x;   // 0..4095
  out[i] = b2[0];
}

// agg fp32 -> bf16 (runs after MSG's atomics complete)
__global__ __launch_bounds__(256) void cvt_agg_kernel(
    const float* __restrict__ agg, ushort_t* __restrict__ aggb) {
  size_t o = ((size_t)blockIdx.x * 256 + threadIdx.x) * 8;
  *(uint4*)(aggb + o) = cvt8(agg + o);
}

// ---------------------------------------------------------------------------
// bf16-MFMA GEMM v2: C[m][n] = epilogue( sum_k A[m][k]*W[n][k] + bias[n] ).
// A and W both pre-converted bf16 [.,K] row-major.
// BM x 64 tile (BM = 128 or 64), BK=64, 4 waves (2x2), K/V... staging via
// global_load_lds DMA (r8-proven: zero VGPR payload), double-buffered LDS,
// ONE barrier/iter: { barrier (drains DMA -> buf cur ready, prev reads
// done); issue DMA for k+64 into buf^1; compute from cur }.
// LDS rows 128 B; swizzle per rule #21: linear LDS dest, per-lane global
// SOURCE pre-swizzled with byte ^= ((row&7)<<4), reads use the same XOR.
// BM=64 -> grid (64,N/64) = 512 blocks for N=512 GEMMs (2 blocks/CU, the
// r8 fix for 1-block/CU starvation).  BM=128 -> 48 KB LDS, 3 blocks/CU.
// MODE_F1 fuses the final dot with W_f2 (shfl-reduce + atomicAdd).
// ---------------------------------------------------------------------------
enum { MODE_MSG = 0, MODE_GI = 1, MODE_GH = 2, MODE_QKV = 3, MODE_OUT = 4,
       MODE_LIN = 5, MODE_F1 = 6 };

template <int MODE, int BM>
__global__ __launch_bounds__(256, (BM == 64 ? 2 : 3)) void gemm_bt(
    const ushort_t* __restrict__ A, const ushort_t* __restrict__ W,
    const float* __restrict__ bias, int K,
    float* __restrict__ outf, ushort_t* __restrict__ outb,
    const int* __restrict__ edge, float* __restrict__ aggf,
    const ushort_t* __restrict__ hres,
    ushort_t* __restrict__ qb, ushort_t* __restrict__ kb,
    ushort_t* __restrict__ vt, const float* __restrict__ wf2)
{
  constexpr int MI   = BM / 32;       // 16-row A fragments per wave
  constexpr int ASZ  = BM * 128;      // bytes per A buffer
  constexpr int BSZ  = 64 * 128;      // bytes per B buffer
  constexpr int NCHA = BM / 8;        // 1024-B A chunks per tile
  constexpr int NCH  = NCHA + 8;      // + 8 B chunks

  __shared__ ushort_t As[2][BM * 64];
  __shared__ ushort_t Bs[2][64 * 64];

  const int tid  = threadIdx.x;
  const int lane = tid & 63;
  const int wave = tid >> 6;
  const int quad = lane >> 4;
  const int l15  = lane & 15;
  const int m0 = blockIdx.x * BM;
  const int n0 = blockIdx.y * 64;
  const int wm = (wave >> 1) * (BM / 2);
  const int wn = (wave & 1) * 32;
  const int rmask = (l15 & 7) << 4;   // read-side swizzle mask

  // DMA chunk coords: chunk = 8 rows x 128 B; lane covers row lane>>3,
  // 16 B at byte (lane&7)*16; source col pre-swizzled by ((row&7)<<4).
  const int crow  = lane >> 3;                              // 0..7
  const int selem = ((((lane & 7) * 16)) ^ (crow << 4)) >> 1;

  float4v acc[MI][2];
#pragma unroll
  for (int i = 0; i < MI; i++)
#pragma unroll
    for (int j = 0; j < 2; j++)
#pragma unroll
      for (int r = 0; r < 4; r++) acc[i][j][r] = 0.f;

#define ISSUE(KK, BUF)                                                         \
  do {                                                                         \
    _Pragma("unroll")                                                          \
    for (int j_ = 0; j_ < NCH / 4; j_++) {                                     \
      const int c_ = wave + j_ * 4;                                            \
      if (c_ < NCHA) {                                                         \
        const int row_ = c_ * 8 + crow;                                        \
        gload16(A + (size_t)(m0 + row_) * K + (KK) + selem,                    \
                (char*)As + (BUF) * ASZ + c_ * 1024);                          \
      } else {                                                                 \
        const int row_ = (c_ - NCHA) * 8 + crow;                               \
        gload16(W + (size_t)(n0 + row_) * K + (KK) + selem,                    \
                (char*)Bs + (BUF) * BSZ + (c_ - NCHA) * 1024);                 \
      }                                                                        \
    }                                                                          \
  } while (0)

  ISSUE(0, 0);
  int cur = 0;

  for (int k0 = 0; k0 < K; k0 += 64) {
    __syncthreads();   // drains DMA (buf cur ready) + prev reads of cur^1 done
    if (k0 + 64 < K) ISSUE(k0 + 64, cur ^ 1);

#pragma unroll
    for (int ks = 0; ks < 2; ks++) {
      short8 af[MI], bfr[2];
#pragma unroll
      for (int i = 0; i < MI; i++)
        af[i] = *(const short8*)((char*)As + cur * ASZ +
                 (wm + i * 16 + l15) * 128 + ((ks * 64 + quad * 16) ^ rmask));
#pragma unroll
      for (int j = 0; j < 2; j++)
        bfr[j] = *(const short8*)((char*)Bs + cur * BSZ +
                 (wn + j * 16 + l15) * 128 + ((ks * 64 + quad * 16) ^ rmask));
#pragma unroll
      for (int i = 0; i < MI; i++)
#pragma unroll
        for (int j = 0; j < 2; j++)
          acc[i][j] = __builtin_amdgcn_mfma_f32_16x16x32_bf16(af[i], bfr[j],
                                                              acc[i][j], 0, 0, 0);
    }
    cur ^= 1;
  }
#undef ISSUE

  if constexpr (MODE == MODE_F1) {
    // fused: out[row] += sum_col relu(f1) * wf2[col]  (out pre-init'd to b_f2)
    float fsum[MI][4];
#pragma unroll
    for (int i = 0; i < MI; i++)
#pragma unroll
      for (int r = 0; r < 4; r++) fsum[i][r] = 0.f;
#pragma unroll
    for (int j = 0; j < 2; j++) {
      const int col = n0 + wn + j * 16 + l15;
      const float bv = bias[col];
      const float wv = wf2[col];
#pragma unroll
      for (int i = 0; i < MI; i++)
#pragma unroll
        for (int r = 0; r < 4; r++)
          fsum[i][r] += fmaxf(acc[i][j][r] + bv, 0.f) * wv;
    }
#pragma unroll
    for (int i = 0; i < MI; i++)
#pragma unroll
      for (int r = 0; r < 4; r++) {
        float s = fsum[i][r];
        s += __shfl_xor(s, 1, 64); s += __shfl_xor(s, 2, 64);
        s += __shfl_xor(s, 4, 64); s += __shfl_xor(s, 8, 64);
        if (l15 == 0)
          atomicAdd(&outf[m0 + wm + i * 16 + quad * 4 + r], s);
      }
  } else {
#pragma unroll
    for (int j = 0; j < 2; j++) {
      const int col = n0 + wn + j * 16 + l15;
      const float bv = bias[col];
#pragma unroll
      for (int i = 0; i < MI; i++) {
#pragma unroll
        for (int r = 0; r < 4; r++) {
          const int row = m0 + wm + i * 16 + quad * 4 + r;
          float v = acc[i][j][r] + bv;
          if constexpr (MODE == MODE_MSG) {
            v = fmaxf(v, 0.f);
            const int dst = edge[E_N + row] & (E_N - 1);  // edge_index[1][row]
            atomicAdd(&aggf[(size_t)dst * H_N + col], v);
          } else if constexpr (MODE == MODE_GI || MODE == MODE_GH) {
            outb[(size_t)row * H3_N + col] = f2bf(v);
          } else if constexpr (MODE == MODE_QKV) {
            const int part = col >> 9;         // 0=q 1=k 2=v
            const int hh   = (col >> 7) & 3;
            const int d    = col & 127;
            const ushort_t bvv = f2bf(v);
            if (part == 0)      qb[((size_t)hh * E_N + row) * HD_N + d] = bvv;
            else if (part == 1) kb[((size_t)hh * E_N + row) * HD_N + d] = bvv;
            else                vt[((size_t)hh * HD_N + d) * E_N + row] = bvv;  // V^T
          } else if constexpr (MODE == MODE_OUT) {
            v += bf2f(hres[(size_t)row * H_N + col]);   // residual y = o + h
            outf[(size_t)row * H_N + col] = v;
          } else {  // MODE_LIN
            outb[(size_t)row * H_N + col] = f2bf(fmaxf(v, 0.f));
          }
        }
      }
    }
  }
}

// ---------------------------------------------------------------------------
// Flash attention v8 (unchanged from r8: 100.6us, no spill): K/V staged via
// global_load_lds DMA, double-buffered, ONE barrier per KV iteration.
// Swizzle per rule #21 (linear LDS dest + pre-swizzled global source).
// grid 256 1-D: head = bid&3 -> one head per XCD, K/V L2-resident.
// 8 waves; waves 0-3: KV [0,2048), waves 4-7: KV [2048,4096); LDS merge.
// ---------------------------------------------------------------------------
__global__ __launch_bounds__(512, 2) void attn_kernel(
    const ushort_t* __restrict__ Qg, const ushort_t* __restrict__ Kg,
    const ushort_t* __restrict__ Vtg, ushort_t* __restrict__ Ob)
{
  const int bid  = blockIdx.x;
  const int head = bid & 3;
  const int qb0  = (bid >> 2) * 64;
  const int tid  = threadIdx.x;
  const int wave = tid >> 6;
  const int grp  = wave >> 2;     // 0/1: which KV half
  const int w4   = wave & 3;      // which 16-row Q sub-tile / staging chunk set
  const int lane = tid & 63;
  const int quad = lane >> 4;
  const int l15  = lane & 15;

  __shared__ ushort_t Ks[2][2][64][128];   // [grp][buf], swizzled, 65536 B
  __shared__ ushort_t Vs[2][2][128][64];   // [grp][buf], swizzled, 65536 B
  __shared__ ushort_t Ps[8][16][64];       // per-wave, swizzled, 16384 B
  char* Psc = (char*)Ps + wave * 2048;

  const ushort_t* Qhead  = Qg  + (size_t)head * E_N * HD_N;
  const ushort_t* Khead  = Kg  + (size_t)head * E_N * HD_N;
  const ushort_t* Vthead = Vtg + (size_t)head * HD_N * E_N;

  // Q A-fragments: loop-invariant, in registers.
  short8 aq[4];
#pragma unroll
  for (int ks = 0; ks < 4; ks++)
    aq[ks] = *(const short8*)(Qhead +
        (size_t)(qb0 + w4 * 16 + l15) * HD_N + ks * 32 + quad * 8);

  float4v oacc[8];
#pragma unroll
  for (int i = 0; i < 8; i++)
#pragma unroll
    for (int r = 0; r < 4; r++) oacc[i][r] = 0.f;
  float mprev[4], lsum[4];
#pragma unroll
  for (int r = 0; r < 4; r++) { mprev[r] = -1e30f; lsum[r] = 0.f; }

  const float scale = 0.088388347648318447f;  // 1/sqrt(128)
  const int q15sw = (l15 & 7) << 4;           // read-side swizzle mask

  const int kt0 = grp * 2048;

#define ISSUE(KT, BUF)                                                         \
  do {                                                                         \
    char* kb_ = (char*)Ks + ((grp * 2 + (BUF)) << 14);                         \
    char* vb_ = (char*)Vs + ((grp * 2 + (BUF)) << 14);                         \
    _Pragma("unroll")                                                          \
    for (int i_ = 0; i_ < 4; i_++) {                                           \
      const int c_ = w4 * 4 + i_;                                              \
      const int krow_ = 4 * c_ + (lane >> 4);      /* tile row 0..63 */        \
      gload16(Khead + (size_t)((KT) + krow_) * HD_N +                          \
                  (((((lane & 15) * 16)) ^ ((krow_ & 7) << 4)) >> 1),          \
              kb_ + c_ * 1024);                                                \
      const int vrow_ = 8 * c_ + (lane >> 3);      /* tile row 0..127 */       \
      gload16(Vthead + (size_t)vrow_ * E_N + (KT) +                            \
                  (((((lane & 7) * 16)) ^ ((lane >> 3) << 4)) >> 1),           \
              vb_ + c_ * 1024);                                                \
    }                                                                          \
  } while (0)

  ISSUE(kt0, 0);   // prologue: tile 0
  int cur = 0;

  for (int it = 0; it < 32; it++) {
    __syncthreads();   // drains DMA (tile it ready) + tile it-1 reads done
    if (it + 1 < 32) ISSUE(kt0 + (it + 1) * 64, cur ^ 1);

    const char* kt_ = (char*)Ks + ((grp * 2 + cur) << 14);
    const char* vt_ = (char*)Vs + ((grp * 2 + cur) << 14);

    float4v sacc[4];
#pragma unroll
    for (int j = 0; j < 4; j++)
#pragma unroll
      for (int r = 0; r < 4; r++) sacc[j][r] = 0.f;
#pragma unroll
    for (int ks = 0; ks < 4; ks++) {
#pragma unroll
      for (int j = 0; j < 4; j++) {
        short8 bk = *(const short8*)(kt_ + (j * 16 + l15) * 256 +
                                     ((ks * 64 + quad * 16) ^ q15sw));
        sacc[j] = __builtin_amdgcn_mfma_f32_16x16x32_bf16(aq[ks], bk, sacc[j], 0, 0, 0);
      }
    }

    float alpha[4], pv[4][4];
#pragma unroll
    for (int r = 0; r < 4; r++) {
      float mx = -1e30f;
#pragma unroll
      for (int j = 0; j < 4; j++) { float s = sacc[j][r] * scale; pv[j][r] = s; mx = fmaxf(mx, s); }
#pragma unroll
      for (int off = 1; off < 16; off <<= 1) mx = fmaxf(mx, __shfl_xor(mx, off, 64));
      float mnew = fmaxf(mprev[r], mx);
      alpha[r] = __expf(mprev[r] - mnew);
      float ss = 0.f;
#pragma unroll
      for (int j = 0; j < 4; j++) { float p = __expf(pv[j][r] - mnew); pv[j][r] = p; ss += p; }
#pragma unroll
      for (int off = 1; off < 16; off <<= 1) ss += __shfl_xor(ss, off, 64);
      lsum[r] = lsum[r] * alpha[r] + ss;
      mprev[r] = mnew;
    }
#pragma unroll
    for (int i = 0; i < 8; i++)
#pragma unroll
      for (int r = 0; r < 4; r++) oacc[i][r] *= alpha[r];

    // Ps write (wave-private, swizzled): within-wave lgkmcnt order, no barrier
#pragma unroll
    for (int j = 0; j < 4; j++)
#pragma unroll
      for (int r = 0; r < 4; r++) {
        const int prow = quad * 4 + r;
        *(ushort_t*)(Psc + prow * 128 +
                     ((2 * (j * 16 + l15)) ^ ((prow & 7) << 4))) = f2bf(pv[j][r]);
      }

#pragma unroll
    for (int ks2 = 0; ks2 < 2; ks2++) {
      short8 ap = *(const short8*)(Psc + l15 * 128 +
                                   ((ks2 * 64 + quad * 16) ^ q15sw));
#pragma unroll
      for (int j = 0; j < 8; j++) {
        short8 bv = *(const short8*)(vt_ + (j * 16 + l15) * 128 +
                                     ((ks2 * 64 + quad * 16) ^ q15sw));
        oacc[j] = __builtin_amdgcn_mfma_f32_16x16x32_bf16(ap, bv, oacc[j], 0, 0, 0);
      }
    }
    cur ^= 1;
  }
#undef ISSUE

  // ---- merge the two KV halves (flash combine), group1 -> LDS -> group0 ----
  __syncthreads();
  float* mO  = (float*)Ks;   // [64][128] fp32 = 32768 B (Ks region is 64 KB)
  float* mML = (float*)Vs;   // [64][2]   fp32
  if (grp == 1) {
#pragma unroll
    for (int j = 0; j < 8; j++)
#pragma unroll
      for (int r = 0; r < 4; r++)
        mO[(w4 * 16 + quad * 4 + r) * 128 + j * 16 + l15] = oacc[j][r];
    if (l15 == 0) {
#pragma unroll
      for (int r = 0; r < 4; r++) {
        mML[(w4 * 16 + quad * 4 + r) * 2 + 0] = mprev[r];
        mML[(w4 * 16 + quad * 4 + r) * 2 + 1] = lsum[r];
      }
    }
  }
  __syncthreads();
  if (grp == 0) {
    float s0[4], s1[4];
#pragma unroll
    for (int r = 0; r < 4; r++) {
      int rr = w4 * 16 + quad * 4 + r;
      float m1 = mML[rr * 2 + 0], l1 = mML[rr * 2 + 1];
      float m  = fmaxf(mprev[r], m1);
      float e0 = __expf(mprev[r] - m);
      float e1 = __expf(m1 - m);
      float inv = 1.f / (lsum[r] * e0 + l1 * e1);
      s0[r] = e0 * inv;
      s1[r] = e1 * inv;
    }
#pragma unroll
    for (int j = 0; j < 8; j++)
#pragma unroll
      for (int r = 0; r < 4; r++) {
        int row = qb0 + w4 * 16 + quad * 4 + r;
        int col = head * HD_N + j * 16 + l15;
        float o1 = mO[(w4 * 16 + quad * 4 + r) * 128 + j * 16 + l15];
        Ob[(size_t)row * H_N + col] = f2bf(oacc[j][r] * s0[r] + o1 * s1[r]);
      }
  }
}

// ---------------------------------------------------------------------------
// GRU elementwise, vectorized: each thread handles 8 contiguous cols.
__global__ __launch_bounds__(256) void gru_kernel(
    const ushort_t* __restrict__ gib, const ushort_t* __restrict__ ghb,
    const float* __restrict__ x, ushort_t* __restrict__ hb) {
  int t = blockIdx.x * 256 + threadIdx.x;         // E*H/8 threads
  int e = t >> 6, j8 = (t & 63) * 8;
  size_t b = (size_t)e * H3_N + j8;
  short8 vir = *(const short8*)(gib + b);
  short8 viz = *(const short8*)(gib + b + 512);
  short8 vin = *(const short8*)(gib + b + 1024);
  short8 vhr = *(const short8*)(ghb + b);
  short8 vhz = *(const short8*)(ghb + b + 512);
  short8 vhn = *(const short8*)(ghb + b + 1024);
  size_t xo = (size_t)e * H_N + j8;
  float4 x0 = *(const float4*)(x + xo);
  float4 x1 = *(const float4*)(x + xo + 4);
  float xv[8] = {x0.x, x0.y, x0.z, x0.w, x1.x, x1.y, x1.z, x1.w};
  union { ushort_t u[8]; uint4 v; } o;
#pragma unroll
  for (int i = 0; i < 8; i++) {
    float ir = bf2f((ushort_t)vir[i]), iz = bf2f((ushort_t)viz[i]), inn = bf2f((ushort_t)vin[i]);
    float hr = bf2f((ushort_t)vhr[i]), hz = bf2f((ushort_t)vhz[i]), hn  = bf2f((ushort_t)vhn[i]);
    float r = 1.f / (1.f + __expf(-(ir + hr)));
    float z = 1.f / (1.f + __expf(-(iz + hz)));
    float n = tanhf(inn + r * hn);
    o.u[i] = f2bf((1.f - z) * n + z * xv[i]);
  }
  *(uint4*)(hb + xo) = o.v;
}

__global__ __launch_bounds__(256) void ln_kernel(
    const float* __restrict__ y, const float* __restrict__ g,
    const float* __restrict__ b, ushort_t* __restrict__ yn) {
  int wave = threadIdx.x >> 6, lane = threadIdx.x & 63;
  int row = blockIdx.x * 4 + wave;
  const float* yr = y + (size_t)row * H_N;
  float v[8], s = 0.f;
#pragma unroll
  for (int i = 0; i < 8; i++) { v[i] = yr[lane + i * 64]; s += v[i]; }
#pragma unroll
  for (int off = 1; off < 64; off <<= 1) s += __shfl_xor(s, off, 64);
  float mu = s * (1.f / 512.f);
  float q = 0.f;
#pragma unroll
  for (int i = 0; i < 8; i++) { float d = v[i] - mu; q += d * d; }
#pragma unroll
  for (int off = 1; off < 64; off <<= 1) q += __shfl_xor(q, off, 64);
  float rstd = rsqrtf(q * (1.f / 512.f) + 1e-5f);
#pragma unroll
  for (int i = 0; i < 8; i++) {
    int c = lane + i * 64;
    yn[(size_t)row * H_N + c] = f2bf((v[i] - mu) * rstd * g[c] + b[c]);
  }
}

// ---------------------------------------------------------------------------
extern "C" void kernel_launch(void* const* d_in, const int* in_sizes, int n_in,
                              void* d_out, int out_size, void* d_ws, size_t ws_size,
                              hipStream_t stream) {
  const float* x     = (const float*)d_in[0];
  const int*   edge  = (const int*)d_in[1];
  const float* W_msg = (const float*)d_in[2];
  const float* b_msg = (const float*)d_in[3];
  const float* W_ih  = (const float*)d_in[4];
  const float* b_ih  = (const float*)d_in[5];
  const float* W_hh  = (const float*)d_in[6];
  const float* b_hh  = (const float*)d_in[7];
  const float* W_in  = (const float*)d_in[8];
  const float* b_in  = (const float*)d_in[9];
  const float* W_out = (const float*)d_in[10];
  const float* b_out = (const float*)d_in[11];
  const float* ln_g  = (const float*)d_in[12];
  const float* ln_b  = (const float*)d_in[13];
  const float* W_lin = (const float*)d_in[14];
  const float* b_lin = (const float*)d_in[15];
  const float* W_f1  = (const float*)d_in[16];
  const float* b_f1  = (const float*)d_in[17];
  const float* W_f2  = (const float*)d_in[18];
  const float* b_f2  = (const float*)d_in[19];

  char* ws = (char*)d_ws;
  const size_t MB = 1024 * 1024;
  // Workspace (liveness-packed); bf16 x+weights at [33,44).
  float*    agg  = (float*)(ws + 1 * MB);          // [1,9)   prep..cvt_agg
  ushort_t* hb   = (ushort_t*)(ws + 1 * MB);       // [1,5)   gru..OUT (agg dead)
  ushort_t* gib  = (ushort_t*)(ws + 9 * MB);       // [9,21)  bf16 [E][3H], GI..gru
  ushort_t* ghb  = (ushort_t*)(ws + 21 * MB);      // [21,33) bf16 [E][3H], GH..gru
  ushort_t* Qb   = (ushort_t*)(ws + 5 * MB);       // [5,9)   QKV..attn
  ushort_t* Kb   = (ushort_t*)(ws + 9 * MB);       // [9,13)  (gib dead)
  ushort_t* Vt   = (ushort_t*)(ws + 13 * MB);      // [13,17)
  ushort_t* ob   = (ushort_t*)(ws + 17 * MB);      // [17,21) attn..OUT
  float*    y    = (float*)(ws + 21 * MB);         // [21,29) fp32, OUT..ln (ghb dead)
  ushort_t* ynb  = (ushort_t*)(ws + 29 * MB);      // [29,31) ln..LIN
  ushort_t* gb   = (ushort_t*)(ws + 31 * MB);      // [31,33) LIN..F1
  ushort_t* aggb = (ushort_t*)(ws + 29 * MB);      // [29,33) cvt_agg..GI (dead before ln)
  ushort_t* xb   = (ushort_t*)(ws + 33 * MB);      // [33,37) bf16 x
  ushort_t* Wmsg_b = xb + 2097152;                 // weights bf16, contiguous
  ushort_t* Wih_b  = xb + 2359296;
  ushort_t* Whh_b  = xb + 3145728;
  ushort_t* Win_b  = xb + 3932160;
  ushort_t* Wout_b = xb + 4718592;
  ushort_t* Wlin_b = xb + 4980736;
  ushort_t* Wf1_b  = xb + 5242880;

  prep_kernel<<<4880, 256, 0, stream>>>(
      x, W_msg, W_ih, W_hh, W_in, W_out, W_lin, W_f1, xb,
      (float4*)agg, b_f2, (float*)d_out);

  gemm_bt<MODE_MSG, 64><<<dim3(64, 8), 256, 0, stream>>>(
      xb, Wmsg_b, b_msg, H_N, nullptr, nullptr, edge, agg, nullptr,
      nullptr, nullptr, nullptr, nullptr);

  cvt_agg_kernel<<<1024, 256, 0, stream>>>(agg, aggb);

  gemm_bt<MODE_GI, 128><<<dim3(32, 24), 256, 0, stream>>>(
      aggb, Wih_b, b_ih, H_N, nullptr, gib, nullptr, nullptr, nullptr,
      nullptr, nullptr, nullptr, nullptr);

  gemm_bt<MODE_GH, 128><<<dim3(32, 24), 256, 0, stream>>>(
      xb, Whh_b, b_hh, H_N, nullptr, ghb, nullptr, nullptr, nullptr,
      nullptr, nullptr, nullptr, nullptr);

  gru_kernel<<<1024, 256, 0, stream>>>(gib, ghb, x, hb);

  gemm_bt<MODE_QKV, 128><<<dim3(32, 24), 256, 0, stream>>>(
      hb, Win_b, b_in, H_N, nullptr, nullptr, nullptr, nullptr, nullptr,
      Qb, Kb, Vt, nullptr);

  attn_kernel<<<256, 512, 0, stream>>>(Qb, Kb, Vt, ob);

  gemm_bt<MODE_OUT, 64><<<dim3(64, 8), 256, 0, stream>>>(
      ob, Wout_b, b_out, H_N, y, nullptr, nullptr, nullptr, hb,
      nullptr, nullptr, nullptr, nullptr);

  ln_kernel<<<1024, 256, 0, stream>>>(y, ln_g, ln_b, ynb);

  gemm_bt<MODE_LIN, 64><<<dim3(64, 8), 256, 0, stream>>>(
      ynb, Wlin_b, b_lin, H_N, nullptr, gb, nullptr, nullptr, nullptr,
      nullptr, nullptr, nullptr, nullptr);

  gemm_bt<MODE_F1, 128><<<dim3(32, 16), 256, 0, stream>>>(
      gb, Wf1_b, b_f1, H_N, (float*)d_out, nullptr, nullptr, nullptr, nullptr,
      nullptr, nullptr, nullptr, W_f2);
}